// Round 9
// baseline (483.562 us; speedup 1.0000x reference)
//
#include <hip/hip_runtime.h>
#include <math.h>

#define BB 16
#define CC 256
#define TT 8192
#define EE 32
#define NSPLIT 8

// workspace layout (float offsets)
#define OFF_M   0
#define OFF_VAR (OFF_M + BB*TT)
#define OFF_DEN (OFF_VAR + BB*TT)
#define OFF_Q   (OFF_DEN + 32)
#define OFF_K   (OFF_Q + BB*CC*EE)
#define OFF_GP  (OFF_K + BB*CC*EE)
#define OFF_PCC (OFF_GP + NSPLIT*BB*CC*CC)
// aH/aL (bf16 split of attn) alias the GP region: GP is dead after k_pccred,
// and k_attn (the writer) runs after k_pccred on the same stream.
#define OFF_AH  OFF_GP
#define OFF_AL  (OFF_GP + (BB*CC*CC/2))

typedef __attribute__((ext_vector_type(8))) short bf16x8;
typedef __attribute__((ext_vector_type(4))) float f32x4;
typedef __attribute__((ext_vector_type(4))) unsigned int u32x4;

union FragU { u32x4 u; bf16x8 s; };

__device__ __forceinline__ unsigned pack_hi2(float f0, float f1) {
  return __builtin_amdgcn_perm(__float_as_uint(f1), __float_as_uint(f0), 0x07060302u);
}

__device__ __forceinline__ void split8(const float v[8], u32x4& hi, u32x4& lo) {
  float l[8];
#pragma unroll
  for (int i = 0; i < 8; ++i) {
    float h = __uint_as_float(__float_as_uint(v[i]) & 0xFFFF0000u);
    l[i] = v[i] - h;
  }
#pragma unroll
  for (int g = 0; g < 4; ++g) {
    hi[g] = pack_hi2(v[2 * g], v[2 * g + 1]);
    lo[g] = pack_hi2(l[2 * g], l[2 * g + 1]);
  }
}

// ---------------- stats: mean/var per (b,t), reduce over C ----------------
__global__ __launch_bounds__(256) void k_stats(const float* __restrict__ x,
                                               float* __restrict__ ws) {
  int bid = blockIdx.x;            // BB * (TT/256) = 512
  int b = bid >> 5;
  int t = ((bid & 31) << 8) | threadIdx.x;
  const float* xb = x + (size_t)b * CC * TT + t;
  float sum = 0.f, sq = 0.f;
#pragma unroll 4
  for (int c = 0; c < CC; ++c) {
    float v = xb[(size_t)c * TT];
    sum += v;
    sq = fmaf(v, v, sq);
  }
  float mean = sum * (1.0f / CC);
  float var = (sq - sum * mean) * (1.0f / (CC - 1));   // ddof=1
  ws[OFF_M + b * TT + t] = mean;
  ws[OFF_VAR + b * TT + t] = var;
}

// ---------------- denom[b] = sum_t var[b,t] ----------------
__global__ __launch_bounds__(256) void k_breduce(float* __restrict__ ws) {
  int b = blockIdx.x;              // BB
  const float* v = ws + OFF_VAR + (size_t)b * TT;
  float s = 0.f;
  for (int i = threadIdx.x; i < TT; i += 256) s += v[i];
#pragma unroll
  for (int off = 32; off; off >>= 1) s += __shfl_down(s, off, 64);
  __shared__ float red[4];
  int wid = threadIdx.x >> 6;
  if ((threadIdx.x & 63) == 0) red[wid] = s;
  __syncthreads();
  if (threadIdx.x == 0) ws[OFF_DEN + b] = red[0] + red[1] + red[2] + red[3];
}

// ---------------- centered Gram via bf16 hi/lo split MFMA ----------------
#define GK 32
__global__ __launch_bounds__(512, 4) void k_gram(const float* __restrict__ x,
                                                 float* __restrict__ ws) {
  __shared__ __align__(16) unsigned short AH[128 * GK];
  __shared__ __align__(16) unsigned short AL[128 * GK];
  __shared__ __align__(16) unsigned short BH[128 * GK];
  __shared__ __align__(16) unsigned short BL[128 * GK];

  int blk = blockIdx.x;            // NSPLIT*4*BB = 512
  int s = blk & 7;
  int tij = (blk >> 3) & 3;
  int b = blk >> 5;
  int ti = (tij >> 1) * 128, tj = (tij & 1) * 128;
  bool diag = (ti == tj);
  int k0 = s * (TT / NSPLIT);

  const float* xb = x + (size_t)b * CC * TT;
  const float* mb = ws + OFF_M + (size_t)b * TT + k0;

  int tid = threadIdx.x;
  int lane = tid & 63;
  int w = tid >> 6;                // 0..7
  int wm = (w & 1) * 64;
  int wn = (w >> 1) * 32;
  int fr = lane & 15;
  int g = lane >> 4;

  int sr = tid >> 2;
  int ss = tid & 3;
  int wbase = sr * GK + ((ss ^ ((sr >> 1) & 3)) << 3);

  f32x4 acc[4][2];
  f32x4 z4 = {0.f, 0.f, 0.f, 0.f};
#pragma unroll
  for (int i = 0; i < 4; ++i) { acc[i][0] = z4; acc[i][1] = z4; }

  for (int kc = 0; kc < TT / NSPLIT; kc += GK) {
    const float* mr = mb + kc + ss * 8;
    const float* ar = xb + (size_t)(ti + sr) * TT + k0 + kc + ss * 8;
    {
      float m8[8], a8[8];
      *(f32x4*)&m8[0] = *(const f32x4*)(mr);
      *(f32x4*)&m8[4] = *(const f32x4*)(mr + 4);
      *(f32x4*)&a8[0] = *(const f32x4*)(ar);
      *(f32x4*)&a8[4] = *(const f32x4*)(ar + 4);
#pragma unroll
      for (int i = 0; i < 8; ++i) a8[i] -= m8[i];
      u32x4 hi, lo;
      split8(a8, hi, lo);
      *(u32x4*)&AH[wbase] = hi;
      *(u32x4*)&AL[wbase] = lo;
      if (!diag) {
        const float* br = xb + (size_t)(tj + sr) * TT + k0 + kc + ss * 8;
        float b8[8];
        *(f32x4*)&b8[0] = *(const f32x4*)(br);
        *(f32x4*)&b8[4] = *(const f32x4*)(br + 4);
#pragma unroll
        for (int i = 0; i < 8; ++i) b8[i] -= m8[i];
        split8(b8, hi, lo);
        *(u32x4*)&BH[wbase] = hi;
        *(u32x4*)&BL[wbase] = lo;
      }
    }
    __syncthreads();
    {
      const unsigned short* Bh = diag ? AH : BH;
      const unsigned short* Bl = diag ? AL : BL;
      FragU aH[4], aL[4], bH[2], bL[2];
#pragma unroll
      for (int m = 0; m < 4; ++m) {
        int r = wm + m * 16 + fr;
        int ad = r * GK + ((g ^ ((r >> 1) & 3)) << 3);
        aH[m].u = *(const u32x4*)&AH[ad];
        aL[m].u = *(const u32x4*)&AL[ad];
      }
#pragma unroll
      for (int n = 0; n < 2; ++n) {
        int r = wn + n * 16 + fr;
        int ad = r * GK + ((g ^ ((r >> 1) & 3)) << 3);
        bH[n].u = *(const u32x4*)&Bh[ad];
        bL[n].u = *(const u32x4*)&Bl[ad];
      }
#pragma unroll
      for (int mi = 0; mi < 4; ++mi)
#pragma unroll
        for (int ni = 0; ni < 2; ++ni) {
          acc[mi][ni] = __builtin_amdgcn_mfma_f32_16x16x32_bf16(aH[mi].s, bH[ni].s, acc[mi][ni], 0, 0, 0);
          acc[mi][ni] = __builtin_amdgcn_mfma_f32_16x16x32_bf16(aH[mi].s, bL[ni].s, acc[mi][ni], 0, 0, 0);
          acc[mi][ni] = __builtin_amdgcn_mfma_f32_16x16x32_bf16(aL[mi].s, bH[ni].s, acc[mi][ni], 0, 0, 0);
        }
    }
    __syncthreads();
  }

  float* gp = ws + OFF_GP + ((size_t)s * BB + b) * CC * CC;
  int r4 = g * 4;
#pragma unroll
  for (int mi = 0; mi < 4; ++mi) {
    int orow = ti + wm + mi * 16 + r4;
#pragma unroll
    for (int ni = 0; ni < 2; ++ni) {
      int ocol = tj + wn + ni * 16 + fr;
#pragma unroll
      for (int j = 0; j < 4; ++j)
        gp[(size_t)(orow + j) * CC + ocol] = acc[mi][ni][j];
    }
  }
}

// ---------------- pcc = (sum_s GP) / denom ----------------
__global__ __launch_bounds__(256) void k_pccred(float* __restrict__ ws) {
  size_t idx = ((size_t)blockIdx.x * 256 + threadIdx.x) * 8;  // grid 512
  int b = (int)(idx >> 16);
  float inv = 1.0f / ws[OFF_DEN + b];
  float4 s0 = make_float4(0.f, 0.f, 0.f, 0.f);
  float4 s1 = s0;
#pragma unroll
  for (int s = 0; s < NSPLIT; ++s) {
    const float* g = ws + OFF_GP + (size_t)s * BB * CC * CC + idx;
    float4 a = *(const float4*)g;
    float4 c = *(const float4*)(g + 4);
    s0.x += a.x; s0.y += a.y; s0.z += a.z; s0.w += a.w;
    s1.x += c.x; s1.y += c.y; s1.z += c.z; s1.w += c.w;
  }
  float* o = ws + OFF_PCC + idx;
  *(float4*)o = make_float4(s0.x * inv, s0.y * inv, s0.z * inv, s0.w * inv);
  *(float4*)(o + 4) = make_float4(s1.x * inv, s1.y * inv, s1.z * inv, s1.w * inv);
}

// ---------------- q,k = pcc @ W^T + b  (256 blocks, no LDS) ----------------
__global__ __launch_bounds__(256) void k_qk(const float* __restrict__ qw,
                                            const float* __restrict__ qb,
                                            const float* __restrict__ kw,
                                            const float* __restrict__ kb,
                                            float* __restrict__ ws) {
  int blk = blockIdx.x;            // BB*16 = 256
  int b = blk >> 4;
  int c0 = (blk & 15) << 4;        // 16 rows per block
  int tid = threadIdx.x;
  int r = tid >> 4;                // 0..15
  int e2 = (tid & 15) * 2;         // 2 e's per thread
  float aq[2] = {qb[e2], qb[e2 + 1]};
  float ak[2] = {kb[e2], kb[e2 + 1]};
  const float* pr = ws + OFF_PCC + ((size_t)b * CC + c0 + r) * CC;
  const float* wq0 = qw + (size_t)e2 * CC;
  const float* wq1 = wq0 + CC;
  const float* wk0 = kw + (size_t)e2 * CC;
  const float* wk1 = wk0 + CC;
  for (int d = 0; d < CC; d += 4) {
    float4 p4 = *(const float4*)(pr + d);
    float4 q0 = *(const float4*)(wq0 + d);
    float4 q1 = *(const float4*)(wq1 + d);
    float4 k0 = *(const float4*)(wk0 + d);
    float4 k1 = *(const float4*)(wk1 + d);
    aq[0] = fmaf(p4.x, q0.x, aq[0]); aq[0] = fmaf(p4.y, q0.y, aq[0]);
    aq[0] = fmaf(p4.z, q0.z, aq[0]); aq[0] = fmaf(p4.w, q0.w, aq[0]);
    aq[1] = fmaf(p4.x, q1.x, aq[1]); aq[1] = fmaf(p4.y, q1.y, aq[1]);
    aq[1] = fmaf(p4.z, q1.z, aq[1]); aq[1] = fmaf(p4.w, q1.w, aq[1]);
    ak[0] = fmaf(p4.x, k0.x, ak[0]); ak[0] = fmaf(p4.y, k0.y, ak[0]);
    ak[0] = fmaf(p4.z, k0.z, ak[0]); ak[0] = fmaf(p4.w, k0.w, ak[0]);
    ak[1] = fmaf(p4.x, k1.x, ak[1]); ak[1] = fmaf(p4.y, k1.y, ak[1]);
    ak[1] = fmaf(p4.z, k1.z, ak[1]); ak[1] = fmaf(p4.w, k1.w, ak[1]);
  }
  float* qo = ws + OFF_Q + ((size_t)b * CC + c0 + r) * EE + e2;
  qo[0] = aq[0]; qo[1] = aq[1];
  float* ko = ws + OFF_K + ((size_t)b * CC + c0 + r) * EE + e2;
  ko[0] = ak[0]; ko[1] = ak[1];
}

// ------- scores + softmax -> attn (fp32 to d_out tail, bf16 hi/lo to ws) -------
// 256 blocks, 16 rows each; 16 threads/row, 16 contiguous d per thread.
__global__ __launch_bounds__(256) void k_attn(float* __restrict__ out,
                                              float* __restrict__ ws) {
  __shared__ float kl[CC][36];
  int blk = blockIdx.x;            // BB*16 = 256
  int b = blk >> 4;
  int c0 = (blk & 15) << 4;
  int tid = threadIdx.x;
  const float* kv = ws + OFF_K + (size_t)b * CC * EE;
#pragma unroll
  for (int p = 0; p < 8; ++p) {
    int flat = (tid + 256 * p) * 4;
    int d = flat >> 5, e = flat & 31;
    *(float4*)&kl[d][e] = *(const float4*)(kv + flat);
  }
  __syncthreads();
  int r = tid >> 4, dg = tid & 15;
  const float* q = ws + OFF_Q + ((size_t)b * CC + c0 + r) * EE;
  float qv[EE];
#pragma unroll
  for (int j = 0; j < EE; j += 4) {
    float4 t4 = *(const float4*)(q + j);
    qv[j] = t4.x; qv[j + 1] = t4.y; qv[j + 2] = t4.z; qv[j + 3] = t4.w;
  }
  float sc[16];
  float mx = -1e30f;
#pragma unroll
  for (int i = 0; i < 16; ++i) {
    int d = dg * 16 + i;
    float s = 0.f;
#pragma unroll
    for (int u = 0; u < EE; u += 4) {
      float4 k4 = *(const float4*)&kl[d][u];
      s = fmaf(qv[u], k4.x, s);
      s = fmaf(qv[u + 1], k4.y, s);
      s = fmaf(qv[u + 2], k4.z, s);
      s = fmaf(qv[u + 3], k4.w, s);
    }
    s *= 0.0625f;                  // 1/sqrt(256)
    sc[i] = s;
    mx = fmaxf(mx, s);
  }
  mx = fmaxf(mx, __shfl_xor(mx, 1));
  mx = fmaxf(mx, __shfl_xor(mx, 2));
  mx = fmaxf(mx, __shfl_xor(mx, 4));
  mx = fmaxf(mx, __shfl_xor(mx, 8));
  float sum = 0.f;
#pragma unroll
  for (int i = 0; i < 16; ++i) { sc[i] = __expf(sc[i] - mx); sum += sc[i]; }
  sum += __shfl_xor(sum, 1);
  sum += __shfl_xor(sum, 2);
  sum += __shfl_xor(sum, 4);
  sum += __shfl_xor(sum, 8);
  float inv = 1.0f / sum;
  size_t rowoff = ((size_t)b * CC + c0 + r) * CC + dg * 16;
  float* ao = out + (size_t)BB * CC * TT + rowoff;
  unsigned short* aHp = (unsigned short*)(ws + OFF_AH) + rowoff;
  unsigned short* aLp = (unsigned short*)(ws + OFF_AL) + rowoff;
#pragma unroll
  for (int gi = 0; gi < 2; ++gi) {
    float v8[8];
#pragma unroll
    for (int j = 0; j < 8; ++j) v8[j] = sc[gi * 8 + j] * inv;
    *(float4*)(ao + gi * 8) = make_float4(v8[0], v8[1], v8[2], v8[3]);
    *(float4*)(ao + gi * 8 + 4) = make_float4(v8[4], v8[5], v8[6], v8[7]);
    u32x4 hi, lo;
    split8(v8, hi, lo);
    *(u32x4*)&aHp[gi * 8] = hi;
    *(u32x4*)&aLp[gi * 8] = lo;
  }
}

// ---------------- out = attn @ x : LDS-staged B, bf16 split MFMA ----------------
// x chunks (32 d x 128 t) staged double-buffered via coalesced dwordx4;
// column-XOR swizzle (col ^ ((row>>3)&1)<<4) makes frag b32 reads 2-way (free).
__global__ __launch_bounds__(256, 3) void k_out(const float* __restrict__ x,
                                                const float* __restrict__ ws_c,
                                                float* __restrict__ out) {
  __shared__ float Xs[2][32][132];

  int blk = blockIdx.x;            // 16*2*64 = 2048
  int tt = blk & 63;
  int ct = (blk >> 6) & 1;
  int b = blk >> 7;
  int t0 = tt << 7;
  int c0 = ct << 7;

  const float* xb = x + (size_t)b * CC * TT;
  const unsigned short* aHb = (const unsigned short*)(ws_c + OFF_AH);
  const unsigned short* aLb = (const unsigned short*)(ws_c + OFF_AL);

  int tid = threadIdx.x;
  int lane = tid & 63;
  int w = tid >> 6;
  int wm = (w >> 1) * 64, wn = (w & 1) * 64;
  int fr = lane & 15;
  int fkb = (lane >> 4) * 8;
  int vg = ((fkb >> 3) & 1) << 4;  // frag-read column swizzle

  f32x4 acc[4][4];
  f32x4 z4 = {0.f, 0.f, 0.f, 0.f};
#pragma unroll
  for (int i = 0; i < 4; ++i)
#pragma unroll
    for (int j = 0; j < 4; ++j) acc[i][j] = z4;

  size_t arow[4];
#pragma unroll
  for (int m = 0; m < 4; ++m)
    arow[m] = ((size_t)b * CC + c0 + wm + m * 16 + fr) * CC + fkb;

  // staging map: slot -> (row=d, col4=t offset)
  int srow[4], scol[4], scols[4];
#pragma unroll
  for (int rr = 0; rr < 4; ++rr) {
    int slot = tid + rr * 256;
    srow[rr] = slot >> 5;
    scol[rr] = (slot & 31) << 2;
    scols[rr] = scol[rr] ^ (((srow[rr] >> 3) & 1) << 4);
  }

  float4 pf[4];
#pragma unroll
  for (int rr = 0; rr < 4; ++rr)
    pf[rr] = *(const float4*)(xb + (size_t)srow[rr] * TT + t0 + scol[rr]);
#pragma unroll
  for (int rr = 0; rr < 4; ++rr)
    *(float4*)&Xs[0][srow[rr]][scols[rr]] = pf[rr];
  __syncthreads();

  for (int kc = 0; kc < CC; kc += 32) {
    int cur = (kc >> 5) & 1;
    bool more = (kc + 32) < CC;
    if (more) {
#pragma unroll
      for (int rr = 0; rr < 4; ++rr)
        pf[rr] = *(const float4*)(xb + (size_t)(kc + 32 + srow[rr]) * TT + t0 + scol[rr]);
    }

    FragU aH[4], aL[4], bH[4], bL[4];
#pragma unroll
    for (int m = 0; m < 4; ++m) {
      aH[m].u = *(const u32x4*)&aHb[arow[m] + kc];
      aL[m].u = *(const u32x4*)&aLb[arow[m] + kc];
    }
#pragma unroll
    for (int n = 0; n < 4; ++n) {
      int tn = wn + n * 16 + fr;
      int tns = tn ^ vg;
      float b8[8];
#pragma unroll
      for (int j = 0; j < 8; ++j)
        b8[j] = Xs[cur][fkb + j][tns];
      split8(b8, bH[n].u, bL[n].u);
    }
#pragma unroll
    for (int mi = 0; mi < 4; ++mi)
#pragma unroll
      for (int ni = 0; ni < 4; ++ni) {
        acc[mi][ni] = __builtin_amdgcn_mfma_f32_16x16x32_bf16(aH[mi].s, bH[ni].s, acc[mi][ni], 0, 0, 0);
        acc[mi][ni] = __builtin_amdgcn_mfma_f32_16x16x32_bf16(aH[mi].s, bL[ni].s, acc[mi][ni], 0, 0, 0);
        acc[mi][ni] = __builtin_amdgcn_mfma_f32_16x16x32_bf16(aL[mi].s, bH[ni].s, acc[mi][ni], 0, 0, 0);
      }
    __syncthreads();
    if (more) {
#pragma unroll
      for (int rr = 0; rr < 4; ++rr)
        *(float4*)&Xs[cur ^ 1][srow[rr]][scols[rr]] = pf[rr];
    }
    __syncthreads();
  }

  int r4 = (lane >> 4) * 4;
#pragma unroll
  for (int mi = 0; mi < 4; ++mi) {
    int orow = c0 + wm + mi * 16 + r4;
#pragma unroll
    for (int ni = 0; ni < 4; ++ni) {
      int ocol = t0 + wn + ni * 16 + fr;
#pragma unroll
      for (int j = 0; j < 4; ++j)
        out[((size_t)b * CC + orow + j) * TT + ocol] = acc[mi][ni][j];
    }
  }
}

extern "C" void kernel_launch(void* const* d_in, const int* in_sizes, int n_in,
                              void* d_out, int out_size, void* d_ws, size_t ws_size,
                              hipStream_t stream) {
  (void)in_sizes; (void)n_in; (void)out_size; (void)ws_size;
  const float* x = (const float*)d_in[0];
  const float* qw = (const float*)d_in[1];
  const float* qb = (const float*)d_in[2];
  const float* kw = (const float*)d_in[3];
  const float* kb = (const float*)d_in[4];
  float* out = (float*)d_out;
  float* ws = (float*)d_ws;

  hipLaunchKernelGGL(k_stats, dim3(BB * 32), dim3(256), 0, stream, x, ws);
  hipLaunchKernelGGL(k_breduce, dim3(BB), dim3(256), 0, stream, ws);
  hipLaunchKernelGGL(k_gram, dim3(NSPLIT * 4 * BB), dim3(512), 0, stream, x, ws);
  hipLaunchKernelGGL(k_pccred, dim3(512), dim3(256), 0, stream, ws);
  hipLaunchKernelGGL(k_qk, dim3(BB * 16), dim3(256), 0, stream, qw, qb, kw, kb, ws);
  hipLaunchKernelGGL(k_attn, dim3(BB * 16), dim3(256), 0, stream, out, ws);
  hipLaunchKernelGGL(k_out, dim3(BB * 4 * 32), dim3(256), 0, stream,
                     x, ws, out);
}